// Round 1
// baseline (1170.370 us; speedup 1.0000x reference)
//
#include <hip/hip_runtime.h>

#define WS_ALIGN(x) (((x) + 255) & ~(size_t)255)

// ---------------- degree / norm ----------------
__global__ void k_init_deg(int* deg, int N) {
  int i = blockIdx.x * blockDim.x + threadIdx.x;
  if (i < N) deg[i] = 1;  // self-loop
}

__global__ void k_count(const int* __restrict__ dst, int E, int* __restrict__ deg) {
  int e = blockIdx.x * blockDim.x + threadIdx.x;
  if (e < E) atomicAdd(&deg[dst[e]], 1);
}

__global__ void k_dis(const int* __restrict__ deg, float* __restrict__ dis, int N) {
  int i = blockIdx.x * blockDim.x + threadIdx.x;
  if (i < N) dis[i] = rsqrtf((float)deg[i]);
}

// ---------------- CSR build ----------------
// exclusive scan of (deg[i]-1) over N elements, single block, shfl wave scans
__global__ __launch_bounds__(1024) void k_scan(const int* __restrict__ deg,
                                               int* __restrict__ rowptr,
                                               int* __restrict__ cursor,
                                               int N, int Etot) {
  __shared__ int wsum[16];
  __shared__ int s_carry;
  int tid = threadIdx.x, lane = tid & 63, w = tid >> 6;
  if (tid == 0) { s_carry = 0; rowptr[N] = Etot; }
  __syncthreads();
  for (int base = 0; base < N; base += 1024) {
    int i = base + tid;
    int v = (i < N) ? (deg[i] - 1) : 0;
    int sc = v;
    #pragma unroll
    for (int off = 1; off < 64; off <<= 1) {
      int t = __shfl_up(sc, off);
      if (lane >= off) sc += t;
    }
    if (lane == 63) wsum[w] = sc;
    __syncthreads();
    if (w == 0 && lane < 16) {
      int x = wsum[lane];
      #pragma unroll
      for (int off = 1; off < 16; off <<= 1) {
        int t = __shfl_up(x, off);
        if (lane >= off) x += t;
      }
      wsum[lane] = x;
    }
    __syncthreads();
    int woff = (w == 0) ? 0 : wsum[w - 1];
    int excl = s_carry + woff + sc - v;
    if (i < N) { rowptr[i] = excl; cursor[i] = excl; }
    __syncthreads();
    if (tid == 0) s_carry += wsum[15];
    __syncthreads();
  }
}

__global__ void k_fill(const int* __restrict__ src, const int* __restrict__ dst, int E,
                       int* __restrict__ cursor, int* __restrict__ csr_src) {
  int e = blockIdx.x * blockDim.x + threadIdx.x;
  if (e < E) {
    int d = dst[e];
    int pos = atomicAdd(&cursor[d], 1);
    csr_src[pos] = src[e];
  }
}

// ---------------- GEMM: C[m][n] = (sum_k A[m][k]*B[k][n]) * dis[m] ----------------
#define BM 128
#define BN 128
#define BK 16
__global__ __launch_bounds__(256) void k_gemm_scale(const float* __restrict__ A,
                                                    const float* __restrict__ B,
                                                    const float* __restrict__ dis,
                                                    float* __restrict__ C,
                                                    int M, int Nc, int K) {
  __shared__ float As[BK][BM];
  __shared__ float Bs[BK][BN];
  int tid = threadIdx.x;
  int block_row = blockIdx.x * BM;
  int block_col = blockIdx.y * BN;
  int tr = (tid >> 4) << 3;  // 0..120 step 8
  int tc = (tid & 15) << 3;
  float acc[8][8] = {};
  for (int k0 = 0; k0 < K; k0 += BK) {
    // A tile (BM x BK), transposed into As[k][m]
    for (int t = tid; t < BM * BK / 4; t += 256) {
      int r = t >> 2;
      int cc = (t & 3) << 2;
      int gr = block_row + r;
      float4 v = {0.f, 0.f, 0.f, 0.f};
      if (gr < M) v = *(const float4*)(A + (size_t)gr * K + k0 + cc);
      As[cc + 0][r] = v.x; As[cc + 1][r] = v.y; As[cc + 2][r] = v.z; As[cc + 3][r] = v.w;
    }
    // B tile (BK x BN)
    for (int t = tid; t < BK * BN / 4; t += 256) {
      int r = t >> 5;
      int cc = (t & 31) << 2;
      *(float4*)&Bs[r][cc] = *(const float4*)(B + (size_t)(k0 + r) * Nc + block_col + cc);
    }
    __syncthreads();
    #pragma unroll
    for (int k = 0; k < BK; ++k) {
      float a[8], b[8];
      *(float4*)&a[0] = *(const float4*)&As[k][tr];
      *(float4*)&a[4] = *(const float4*)&As[k][tr + 4];
      *(float4*)&b[0] = *(const float4*)&Bs[k][tc];
      *(float4*)&b[4] = *(const float4*)&Bs[k][tc + 4];
      #pragma unroll
      for (int i = 0; i < 8; ++i)
        #pragma unroll
        for (int j = 0; j < 8; ++j)
          acc[i][j] = fmaf(a[i], b[j], acc[i][j]);
    }
    __syncthreads();
  }
  for (int i = 0; i < 8; ++i) {
    int gr = block_row + tr + i;
    if (gr >= M) break;
    float s = dis[gr];
    for (int j = 0; j < 8; j += 4) {
      float4 v = {acc[i][j] * s, acc[i][j + 1] * s, acc[i][j + 2] * s, acc[i][j + 3] * s};
      *(float4*)(C + (size_t)gr * Nc + block_col + tc + j) = v;
    }
  }
}

// ---------------- aggregation: out[i] = relu?(dis[i]*(sum_in hs[src] + hs[i]) + b) ----------------
__global__ void k_aggregate(const float* __restrict__ hs, const int* __restrict__ rowptr,
                            const int* __restrict__ csr_src, const float* __restrict__ dis,
                            const float* __restrict__ bias, float* __restrict__ out,
                            int F, int do_relu) {
  int node = blockIdx.x;
  int c = threadIdx.x;
  float acc = hs[(size_t)node * F + c];  // self-loop (hs already scaled by dis[src])
  int s = rowptr[node], e = rowptr[node + 1];
  for (int j = s; j < e; ++j) {
    int srcn = csr_src[j];
    acc += hs[(size_t)srcn * F + c];
  }
  acc = acc * dis[node] + bias[c];
  if (do_relu) acc = fmaxf(acc, 0.0f);
  out[(size_t)node * F + c] = acc;
}

// ---------------- decode: out[e] = dot(z[src[e]], z[dst[e]]) over 128 ch ----------------
__global__ __launch_bounds__(256) void k_decode(const float* __restrict__ z,
                                                const int* __restrict__ src,
                                                const int* __restrict__ dst,
                                                float* __restrict__ out, int E) {
  int gw = (int)((blockIdx.x * (size_t)blockDim.x + threadIdx.x) >> 6);
  int lane = threadIdx.x & 63;
  if (gw >= E) return;
  int s = src[gw], d = dst[gw];
  float2 a = ((const float2*)(z + (size_t)s * 128))[lane];
  float2 b = ((const float2*)(z + (size_t)d * 128))[lane];
  float v = a.x * b.x + a.y * b.y;
  #pragma unroll
  for (int off = 32; off; off >>= 1) v += __shfl_down(v, off);
  if (lane == 0) out[gw] = v;
}

extern "C" void kernel_launch(void* const* d_in, const int* in_sizes, int n_in,
                              void* d_out, int out_size, void* d_ws, size_t ws_size,
                              hipStream_t stream) {
  const float* x  = (const float*)d_in[0];
  const int* eidx = (const int*)d_in[1];
  const float* W1 = (const float*)d_in[2];
  const float* b1 = (const float*)d_in[3];
  const float* W2 = (const float*)d_in[4];
  const float* b2 = (const float*)d_in[5];
  float* out = (float*)d_out;

  const int IN_CH = 256, HID = 256, OUT_CH = 128;
  const int N = in_sizes[0] / IN_CH;
  const int E = in_sizes[1] / 2;
  const int* esrc = eidx;
  const int* edst = eidx + E;

  char* p = (char*)d_ws;
  auto alloc = [&](size_t bytes) -> char* { char* r = p; p += WS_ALIGN(bytes); return r; };
  int*   deg    = (int*)  alloc(sizeof(int) * N);
  float* dis    = (float*)alloc(sizeof(float) * N);
  int*   rowptr = (int*)  alloc(sizeof(int) * (N + 1));
  int*   cursor = (int*)  alloc(sizeof(int) * N);
  int*   csr    = (int*)  alloc(sizeof(int) * (size_t)E);
  float* bufA   = (float*)alloc(sizeof(float) * (size_t)N * HID);  // h1s, then h2s
  float* bufB   = (float*)alloc(sizeof(float) * (size_t)N * HID);  // z1, then z2

  const int T = 256;
  hipLaunchKernelGGL(k_init_deg, dim3((N + T - 1) / T), dim3(T), 0, stream, deg, N);
  hipLaunchKernelGGL(k_count, dim3((E + T - 1) / T), dim3(T), 0, stream, edst, E, deg);
  hipLaunchKernelGGL(k_dis, dim3((N + T - 1) / T), dim3(T), 0, stream, deg, dis, N);
  hipLaunchKernelGGL(k_scan, dim3(1), dim3(1024), 0, stream, deg, rowptr, cursor, N, E);
  hipLaunchKernelGGL(k_fill, dim3((E + T - 1) / T), dim3(T), 0, stream, esrc, edst, E, cursor, csr);

  // conv1: h1s = (x @ W1) * dis[row]; z1 = relu(dis*(sum+self)+b1)
  dim3 g1((N + BM - 1) / BM, HID / BN);
  hipLaunchKernelGGL(k_gemm_scale, g1, dim3(256), 0, stream, x, W1, dis, bufA, N, HID, IN_CH);
  hipLaunchKernelGGL(k_aggregate, dim3(N), dim3(HID), 0, stream, bufA, rowptr, csr, dis, b1, bufB, HID, 1);

  // conv2: h2s = (z1 @ W2) * dis[row]; z2 = dis*(sum+self)+b2
  dim3 g2((N + BM - 1) / BM, OUT_CH / BN);
  hipLaunchKernelGGL(k_gemm_scale, g2, dim3(256), 0, stream, bufB, W2, dis, bufA, N, OUT_CH, HID);
  hipLaunchKernelGGL(k_aggregate, dim3(N), dim3(OUT_CH), 0, stream, bufA, rowptr, csr, dis, b2, bufB, OUT_CH, 0);

  // decode
  size_t nwaves = (size_t)E;
  hipLaunchKernelGGL(k_decode, dim3((unsigned)((nwaves * 64 + 255) / 256)), dim3(256), 0, stream,
                     bufB, esrc, edst, out, E);
}

// Round 2
// 942.384 us; speedup vs baseline: 1.2419x; 1.2419x over previous
//
#include <hip/hip_runtime.h>

#define WS_ALIGN(x) (((x) + 255) & ~(size_t)255)

// ---------------- degree / norm ----------------
__global__ void k_init_deg(int* deg, int N) {
  int i = blockIdx.x * blockDim.x + threadIdx.x;
  if (i < N) deg[i] = 1;  // self-loop
}

__global__ void k_count(const int* __restrict__ dst, int E, int* __restrict__ deg) {
  int e = blockIdx.x * blockDim.x + threadIdx.x;
  if (e < E) atomicAdd(&deg[dst[e]], 1);
}

__global__ void k_dis(const int* __restrict__ deg, float* __restrict__ dis, int N) {
  int i = blockIdx.x * blockDim.x + threadIdx.x;
  if (i < N) dis[i] = rsqrtf((float)deg[i]);
}

// ---------------- CSR build ----------------
// exclusive scan of (deg[i]-1), 4 elements/thread, single block
__global__ __launch_bounds__(1024) void k_scan(const int* __restrict__ deg,
                                               int* __restrict__ rowptr,
                                               int* __restrict__ cursor,
                                               int N, int Etot) {
  __shared__ int wsum[16];
  __shared__ int s_carry;
  int tid = threadIdx.x, lane = tid & 63, w = tid >> 6;
  if (tid == 0) { s_carry = 0; rowptr[N] = Etot; }
  __syncthreads();
  for (int base = 0; base < N; base += 4096) {
    int i0 = base + tid * 4;
    int v[4];
    #pragma unroll
    for (int u = 0; u < 4; ++u) {
      int i = i0 + u;
      v[u] = (i < N) ? (deg[i] - 1) : 0;
    }
    int tsum = v[0] + v[1] + v[2] + v[3];
    int sc = tsum;
    #pragma unroll
    for (int off = 1; off < 64; off <<= 1) {
      int t = __shfl_up(sc, off);
      if (lane >= off) sc += t;
    }
    if (lane == 63) wsum[w] = sc;
    __syncthreads();
    if (w == 0 && lane < 16) {
      int xx = wsum[lane];
      #pragma unroll
      for (int off = 1; off < 16; off <<= 1) {
        int t = __shfl_up(xx, off);
        if (lane >= off) xx += t;
      }
      wsum[lane] = xx;
    }
    __syncthreads();
    int woff = (w == 0) ? 0 : wsum[w - 1];
    int excl = s_carry + woff + (sc - tsum);
    #pragma unroll
    for (int u = 0; u < 4; ++u) {
      int i = i0 + u;
      if (i < N) { rowptr[i] = excl; cursor[i] = excl; }
      excl += v[u];
    }
    __syncthreads();
    if (tid == 0) s_carry += wsum[15];
    __syncthreads();
  }
}

__global__ void k_fill(const int* __restrict__ src, const int* __restrict__ dst, int E,
                       int* __restrict__ cursor, int* __restrict__ csr_src) {
  int e = blockIdx.x * blockDim.x + threadIdx.x;
  if (e < E) {
    int d = dst[e];
    int pos = atomicAdd(&cursor[d], 1);
    csr_src[pos] = src[e];
  }
}

// ---------------- GEMM: C[m][n] = (sum_k A[m][k]*B[k][n]) * dis[m] ----------------
#define BM 128
#define BN 128
#define BK 16
__global__ __launch_bounds__(256) void k_gemm_scale(const float* __restrict__ A,
                                                    const float* __restrict__ B,
                                                    const float* __restrict__ dis,
                                                    float* __restrict__ C,
                                                    int M, int Nc, int K) {
  __shared__ float As[BK][BM];
  __shared__ float Bs[BK][BN];
  int tid = threadIdx.x;
  int block_row = blockIdx.x * BM;
  int block_col = blockIdx.y * BN;
  int tr = (tid >> 4) << 3;
  int tc = (tid & 15) << 3;
  float acc[8][8] = {};
  for (int k0 = 0; k0 < K; k0 += BK) {
    for (int t = tid; t < BM * BK / 4; t += 256) {
      int r = t >> 2;
      int cc = (t & 3) << 2;
      int gr = block_row + r;
      float4 v = {0.f, 0.f, 0.f, 0.f};
      if (gr < M) v = *(const float4*)(A + (size_t)gr * K + k0 + cc);
      As[cc + 0][r] = v.x; As[cc + 1][r] = v.y; As[cc + 2][r] = v.z; As[cc + 3][r] = v.w;
    }
    for (int t = tid; t < BK * BN / 4; t += 256) {
      int r = t >> 5;
      int cc = (t & 31) << 2;
      *(float4*)&Bs[r][cc] = *(const float4*)(B + (size_t)(k0 + r) * Nc + block_col + cc);
    }
    __syncthreads();
    #pragma unroll
    for (int k = 0; k < BK; ++k) {
      float a[8], b[8];
      *(float4*)&a[0] = *(const float4*)&As[k][tr];
      *(float4*)&a[4] = *(const float4*)&As[k][tr + 4];
      *(float4*)&b[0] = *(const float4*)&Bs[k][tc];
      *(float4*)&b[4] = *(const float4*)&Bs[k][tc + 4];
      #pragma unroll
      for (int i = 0; i < 8; ++i)
        #pragma unroll
        for (int j = 0; j < 8; ++j)
          acc[i][j] = fmaf(a[i], b[j], acc[i][j]);
    }
    __syncthreads();
  }
  for (int i = 0; i < 8; ++i) {
    int gr = block_row + tr + i;
    if (gr >= M) break;
    float s = dis[gr];
    for (int j = 0; j < 8; j += 4) {
      float4 v = {acc[i][j] * s, acc[i][j + 1] * s, acc[i][j + 2] * s, acc[i][j + 3] * s};
      *(float4*)(C + (size_t)gr * Nc + block_col + tc + j) = v;
    }
  }
}

// ---------------- aggregation: one wave per node, VEC floats/lane ----------------
// out[i] = relu?(dis[i]*(sum_in hs[src] + hs[i]) + b)
template <int VEC>
__global__ __launch_bounds__(256) void k_agg(const float* __restrict__ hs,
                                             const int* __restrict__ rowptr,
                                             const int* __restrict__ csr,
                                             const float* __restrict__ dis,
                                             const float* __restrict__ bias,
                                             float* __restrict__ out,
                                             int N, int do_relu) {
  const int F = VEC * 64;
  int wid = threadIdx.x >> 6;
  int lane = threadIdx.x & 63;
  int node = blockIdx.x * 4 + wid;
  if (node >= N) return;
  const float* rs = hs + (size_t)node * F + lane * VEC;
  float acc[VEC];
  if (VEC == 4) {
    float4 t = *(const float4*)rs;
    acc[0] = t.x; acc[1] = t.y; acc[2] = t.z; acc[3] = t.w;
  } else {
    float2 t = *(const float2*)rs;
    acc[0] = t.x; acc[1] = t.y;
  }
  int s = rowptr[node], e = rowptr[node + 1];
  int j = s;
  for (; j + 8 <= e; j += 8) {
    int idx[8];
    #pragma unroll
    for (int u = 0; u < 8; ++u) idx[u] = csr[j + u];
    #pragma unroll
    for (int u = 0; u < 8; ++u) {
      const float* r = hs + (size_t)idx[u] * F + lane * VEC;
      if (VEC == 4) {
        float4 t = *(const float4*)r;
        acc[0] += t.x; acc[1] += t.y; acc[2] += t.z; acc[3] += t.w;
      } else {
        float2 t = *(const float2*)r;
        acc[0] += t.x; acc[1] += t.y;
      }
    }
  }
  for (; j < e; ++j) {
    const float* r = hs + (size_t)csr[j] * F + lane * VEC;
    if (VEC == 4) {
      float4 t = *(const float4*)r;
      acc[0] += t.x; acc[1] += t.y; acc[2] += t.z; acc[3] += t.w;
    } else {
      float2 t = *(const float2*)r;
      acc[0] += t.x; acc[1] += t.y;
    }
  }
  float dn = dis[node];
  if (VEC == 4) {
    float4 bv = *(const float4*)(bias + lane * 4);
    float4 o;
    o.x = acc[0] * dn + bv.x; o.y = acc[1] * dn + bv.y;
    o.z = acc[2] * dn + bv.z; o.w = acc[3] * dn + bv.w;
    if (do_relu) {
      o.x = fmaxf(o.x, 0.f); o.y = fmaxf(o.y, 0.f);
      o.z = fmaxf(o.z, 0.f); o.w = fmaxf(o.w, 0.f);
    }
    *(float4*)(out + (size_t)node * F + lane * 4) = o;
  } else {
    float2 bv = *(const float2*)(bias + lane * 2);
    float2 o;
    o.x = acc[0] * dn + bv.x; o.y = acc[1] * dn + bv.y;
    if (do_relu) { o.x = fmaxf(o.x, 0.f); o.y = fmaxf(o.y, 0.f); }
    *(float2*)(out + (size_t)node * F + lane * 2) = o;
  }
}

// ---------------- decode: 8 edges per wave ----------------
__global__ __launch_bounds__(256) void k_decode(const float* __restrict__ z,
                                                const int* __restrict__ src,
                                                const int* __restrict__ dst,
                                                float* __restrict__ out, int E) {
  int wave = (int)((blockIdx.x * 256u + threadIdx.x) >> 6);
  int lane = threadIdx.x & 63;
  int e0 = wave * 8;
  if (e0 >= E) return;
  int cnt = min(8, E - e0);
  float acc[8];
  #pragma unroll
  for (int k = 0; k < 8; ++k) acc[k] = 0.f;
  #pragma unroll
  for (int k = 0; k < 8; ++k) {
    if (k < cnt) {
      int s = src[e0 + k], d = dst[e0 + k];
      float2 a = ((const float2*)(z + (size_t)s * 128))[lane];
      float2 b = ((const float2*)(z + (size_t)d * 128))[lane];
      acc[k] = a.x * b.x + a.y * b.y;
    }
  }
  #pragma unroll
  for (int k = 0; k < 8; ++k) {
    #pragma unroll
    for (int off = 32; off; off >>= 1) acc[k] += __shfl_down(acc[k], off);
  }
  if (lane == 0) {
    if (cnt == 8) {
      float4 o0 = {acc[0], acc[1], acc[2], acc[3]};
      float4 o1 = {acc[4], acc[5], acc[6], acc[7]};
      *(float4*)(out + e0) = o0;
      *(float4*)(out + e0 + 4) = o1;
    } else {
      for (int k = 0; k < cnt; ++k) out[e0 + k] = acc[k];
    }
  }
}

extern "C" void kernel_launch(void* const* d_in, const int* in_sizes, int n_in,
                              void* d_out, int out_size, void* d_ws, size_t ws_size,
                              hipStream_t stream) {
  const float* x  = (const float*)d_in[0];
  const int* eidx = (const int*)d_in[1];
  const float* W1 = (const float*)d_in[2];
  const float* b1 = (const float*)d_in[3];
  const float* W2 = (const float*)d_in[4];
  const float* b2 = (const float*)d_in[5];
  float* out = (float*)d_out;

  const int IN_CH = 256, HID = 256, OUT_CH = 128;
  const int N = in_sizes[0] / IN_CH;
  const int E = in_sizes[1] / 2;
  const int* esrc = eidx;
  const int* edst = eidx + E;

  char* p = (char*)d_ws;
  auto alloc = [&](size_t bytes) -> char* { char* r = p; p += WS_ALIGN(bytes); return r; };
  int*   deg    = (int*)  alloc(sizeof(int) * N);
  float* dis    = (float*)alloc(sizeof(float) * N);
  int*   rowptr = (int*)  alloc(sizeof(int) * (N + 1));
  int*   cursor = (int*)  alloc(sizeof(int) * N);
  int*   csr    = (int*)  alloc(sizeof(int) * (size_t)E);
  float* bufA   = (float*)alloc(sizeof(float) * (size_t)N * HID);  // h1s, then h2s
  float* bufB   = (float*)alloc(sizeof(float) * (size_t)N * HID);  // z1, then z2

  const int T = 256;
  hipLaunchKernelGGL(k_init_deg, dim3((N + T - 1) / T), dim3(T), 0, stream, deg, N);
  hipLaunchKernelGGL(k_count, dim3((E + T - 1) / T), dim3(T), 0, stream, edst, E, deg);
  hipLaunchKernelGGL(k_dis, dim3((N + T - 1) / T), dim3(T), 0, stream, deg, dis, N);
  hipLaunchKernelGGL(k_scan, dim3(1), dim3(1024), 0, stream, deg, rowptr, cursor, N, E);
  hipLaunchKernelGGL(k_fill, dim3((E + T - 1) / T), dim3(T), 0, stream, esrc, edst, E, cursor, csr);

  // conv1: h1s = (x @ W1) * dis[row]; z1 = relu(dis*(sum+self)+b1)
  dim3 g1((N + BM - 1) / BM, HID / BN);
  hipLaunchKernelGGL(k_gemm_scale, g1, dim3(256), 0, stream, x, W1, dis, bufA, N, HID, IN_CH);
  hipLaunchKernelGGL((k_agg<4>), dim3((N + 3) / 4), dim3(256), 0, stream,
                     bufA, rowptr, csr, dis, b1, bufB, N, 1);

  // conv2: h2s = (z1 @ W2) * dis[row]; z2 = dis*(sum+self)+b2
  dim3 g2((N + BM - 1) / BM, OUT_CH / BN);
  hipLaunchKernelGGL(k_gemm_scale, g2, dim3(256), 0, stream, bufB, W2, dis, bufA, N, OUT_CH, HID);
  hipLaunchKernelGGL((k_agg<2>), dim3((N + 3) / 4), dim3(256), 0, stream,
                     bufA, rowptr, csr, dis, b2, bufB, N, 0);

  // decode: 8 edges per wave
  int nwaves = (E + 7) / 8;
  hipLaunchKernelGGL(k_decode, dim3((nwaves + 3) / 4), dim3(256), 0, stream,
                     bufB, esrc, edst, out, E);
}